// Round 3
// baseline (846.743 us; speedup 1.0000x reference)
//
#include <hip/hip_runtime.h>

// Problem constants: flow/flowback [B,2,T,H,W] fp32, masks [B,1,T,H,W] fp32.
#define BB 8
#define CC 2
#define TT 8
#define HH 512
#define WW 512
#define HWSZ (HH * WW)                    // 262144 pixels per (b,t) slice
#define NSL (BB * TT)                     // 64 (b,t) slices
#define TOTAL_ELEMS ((double)(BB * CC * TT) * (double)HWSZ)  // 33,554,432 (mean denom)

// clang vector type accepted by __builtin_nontemporal_load (HIP_vector_type is not)
typedef float fvec4 __attribute__((ext_vector_type(4)));

// Unaligned-tolerant loads. gfx950 supports 4B-aligned dwordx2/dwordx4.
__device__ __forceinline__ float2 ld2u(const float* __restrict__ p) {
    float2 v;
    __builtin_memcpy(&v, p, sizeof(float2));
    return v;
}
__device__ __forceinline__ float4 ld4u(const float* __restrict__ p) {
    float4 v;
    __builtin_memcpy(&v, p, sizeof(float4));
    return v;
}
__device__ __forceinline__ fvec4 ld4nt(const float* __restrict__ p) {
    return __builtin_nontemporal_load((const fvec4*)p);
}

// ---------------------------------------------------------------------------
// Repack pass: [B,2,T,H,W] plane-separated -> [slice][H][W][2] interleaved.
// Pure streaming, fully coalesced both sides. One thread = 4 pixels.
// ---------------------------------------------------------------------------
__global__ __launch_bounds__(256) void repack_kernel(
    const float* __restrict__ in,   // [B,2,T,H,W]
    float* __restrict__ out)        // [64][H][W][2]
{
    const int g = blockIdx.x * 256 + threadIdx.x;  // float4-group id
    const int s = g >> 16;                         // 65536 groups per slice
    const int p = (g & 65535) * 4;                 // pixel index in slice
    const int b = s >> 3;                          // T == 8
    const int t = s & 7;
    const float* c0 = in + (b * 16 + t) * HWSZ;    // ((b*2+0)*8+t)*HWSZ
    const float* c1 = c0 + 8 * HWSZ;               // channel stride T*HWSZ
    const float4 a = *(const float4*)(c0 + p);
    const float4 c = *(const float4*)(c1 + p);
    float* o = out + (size_t)s * (HWSZ * 2) + (size_t)p * 2;
    *(float4*)(o)     = make_float4(a.x, c.x, a.y, c.y);  // px p, p+1
    *(float4*)(o + 4) = make_float4(a.z, c.z, a.w, c.w);  // px p+2, p+3
}

// ---------------------------------------------------------------------------
// Bilinear sample from channel-interleaved image [(y*W+x)*2 + c], zeros
// padding, align_corners=True. TWO 16B divergent loads (one per row) instead
// of four 8B loads: each 16B covers both channels of the x-pair.
// ---------------------------------------------------------------------------
__device__ __forceinline__ void bilin2I(const float* __restrict__ pI,
                                        float sx, float sy,
                                        float& r0, float& r1)
{
    const float x0f = floorf(sx);
    const float y0f = floorf(sy);
    const float wx1 = sx - x0f;
    const float wy1 = sy - y0f;
    const int x0 = (int)x0f;
    const int y0 = (int)y0f;
    const int y1 = y0 + 1;

    // x-pair window: pixels [xl, xl+1] with xl = clamp(x0, 0, W-2).
    const int xl = min(max(x0, 0), WW - 2);
    const float ax = (1.f - wx1) * ((x0 >= 0 && x0 < WW) ? 1.f : 0.f);      // tap x0
    const float bx = wx1 * ((x0 + 1 >= 0 && x0 + 1 < WW) ? 1.f : 0.f);      // tap x0+1
    const bool lo_is_x0 = (x0 == xl);
    const float wl = lo_is_x0 ? ax : bx;   // weight on loaded pixel xl
    const float wr = lo_is_x0 ? bx : ax;   // weight on loaded pixel xl+1

    const float wyA = (1.f - wy1) * ((y0 >= 0 && y0 < HH) ? 1.f : 0.f);
    const float wyB = wy1 * ((y1 >= 0 && y1 < HH) ? 1.f : 0.f);
    const int baseA = (min(max(y0, 0), HH - 1) * WW + xl) * 2;
    const int baseB = (min(max(y1, 0), HH - 1) * WW + xl) * 2;

    // (c0[xl], c1[xl], c0[xl+1], c1[xl+1]) per row — 8B-aligned dwordx4.
    const float4 A = ld4u(pI + baseA);
    const float4 B = ld4u(pI + baseB);

    r0 = wyA * (wl * A.x + wr * A.z) + wyB * (wl * B.x + wr * B.z);
    r1 = wyA * (wl * A.y + wr * A.w) + wyB * (wl * B.y + wr * B.w);
}

// Grid: 2048 blocks x 256 threads. blockIdx&7 = XCD (dispatch heuristic);
// each XCD owns 8 consecutive slices; per-slice gather window (flow+flowback
// interleaved = 4MB) matches the per-XCD L2. Masks loaded nontemporal so the
// streamed-once data doesn't evict the gather window.
__global__ __launch_bounds__(256, 6) void flow_loss_i_kernel(
    const float* __restrict__ flowI,
    const float* __restrict__ fbI,
    const float* __restrict__ mask_fw,
    const float* __restrict__ mask_bw,
    double* __restrict__ acc)
{
    const int xcd = blockIdx.x & 7;     // 0..7
    const int o   = blockIdx.x >> 3;    // 0..255: within-XCD block ordinal

    const int g   = o * 256 + threadIdx.x;  // 0..65535 float4-group in slice
    const int pix = g * 4;                  // 4 | 512 -> never straddles a row
    const int xb  = pix & (WW - 1);
    const int y   = pix >> 9;               // W == 512

    float lsum = 0.f;

    for (int sl = 0; sl < 8; ++sl) {
        const int s = xcd * 8 + sl;     // bt slice 0..63
        const float* fI  = flowI + (size_t)s * (HWSZ * 2);
        const float* gI  = fbI   + (size_t)s * (HWSZ * 2);
        const float* mfp = mask_fw + s * HWSZ;
        const float* mbp = mask_bw + s * HWSZ;

        // streamed reads (all coalesced 16B)
        const float4 u0 = *(const float4*)(fI + (size_t)pix * 2);
        const float4 u1 = *(const float4*)(fI + (size_t)pix * 2 + 4);
        const float4 v0 = *(const float4*)(gI + (size_t)pix * 2);
        const float4 v1 = *(const float4*)(gI + (size_t)pix * 2 + 4);
        const fvec4 mfv = ld4nt(mfp + pix);
        const fvec4 mbv = ld4nt(mbp + pix);

        const float fxa[4] = {u0.x, u0.z, u1.x, u1.z};
        const float fya[4] = {u0.y, u0.w, u1.y, u1.w};
        const float gxa[4] = {v0.x, v0.z, v1.x, v1.z};
        const float gya[4] = {v0.y, v0.w, v1.y, v1.w};
        const float mfa[4] = {mfv.x, mfv.y, mfv.z, mfv.w};
        const float mba[4] = {mbv.x, mbv.y, mbv.z, mbv.w};

#pragma unroll
        for (int k = 0; k < 4; ++k) {
            const float xf = (float)(xb + k);
            const float yf = (float)y;
            float wfbx, wfby, wfx, wfy;
            // nextloss term: warp(flowback, flow) + flow
            bilin2I(gI, xf + fxa[k], yf + fya[k], wfbx, wfby);
            // prevloss term: warp(flow, flowback) + flowback
            bilin2I(fI, xf + gxa[k], yf + gya[k], wfx, wfy);
            lsum += mfa[k] * (fabsf(wfbx + fxa[k]) + fabsf(wfby + fya[k]))
                  + mba[k] * (fabsf(wfx  + gxa[k]) + fabsf(wfy  + gya[k]));
        }
    }

    // wave64 reduce
    for (int off = 32; off > 0; off >>= 1)
        lsum += __shfl_down(lsum, off, 64);

    __shared__ float wsum[4];
    const int lane = threadIdx.x & 63;
    const int wv   = threadIdx.x >> 6;
    if (lane == 0) wsum[wv] = lsum;
    __syncthreads();
    if (threadIdx.x == 0) {
        float ssum = wsum[0] + wsum[1] + wsum[2] + wsum[3];
        atomicAdd(acc, (double)ssum);
    }
}

// ---------------------------------------------------------------------------
// Fallback path (previous verified kernel): used when ws_size can't hold the
// interleaved copies. Plane-separated layout, 4x 8B divergent loads per tap.
// ---------------------------------------------------------------------------
__device__ __forceinline__ void bilin2(const float* __restrict__ c0,
                                       const float* __restrict__ c1,
                                       float sx, float sy,
                                       float& r0, float& r1)
{
    const float x0f = floorf(sx);
    const float y0f = floorf(sy);
    const float wx1 = sx - x0f;
    const float wy1 = sy - y0f;
    const int x0 = (int)x0f;
    const int y0 = (int)y0f;
    const int y1 = y0 + 1;

    const int xl = min(max(x0, 0), WW - 2);
    const float ax = (1.f - wx1) * ((x0 >= 0 && x0 < WW) ? 1.f : 0.f);
    const float bx = wx1 * ((x0 + 1 >= 0 && x0 + 1 < WW) ? 1.f : 0.f);
    const bool lo_is_x0 = (x0 == xl);
    const float wl = lo_is_x0 ? ax : bx;
    const float wr = lo_is_x0 ? bx : ax;

    const float wyA = (1.f - wy1) * ((y0 >= 0 && y0 < HH) ? 1.f : 0.f);
    const float wyB = wy1 * ((y1 >= 0 && y1 < HH) ? 1.f : 0.f);
    const int baseA = min(max(y0, 0), HH - 1) * WW + xl;
    const int baseB = min(max(y1, 0), HH - 1) * WW + xl;

    const float2 a0 = ld2u(c0 + baseA);
    const float2 b0 = ld2u(c0 + baseB);
    const float2 a1 = ld2u(c1 + baseA);
    const float2 b1 = ld2u(c1 + baseB);

    r0 = wyA * (wl * a0.x + wr * a0.y) + wyB * (wl * b0.x + wr * b0.y);
    r1 = wyA * (wl * a1.x + wr * a1.y) + wyB * (wl * b1.x + wr * b1.y);
}

__global__ __launch_bounds__(256, 6) void flow_loss_kernel(
    const float* __restrict__ flow,
    const float* __restrict__ flowback,
    const float* __restrict__ mask_fw,
    const float* __restrict__ mask_bw,
    double* __restrict__ acc)
{
    const int xcd = blockIdx.x & 7;
    const int o   = blockIdx.x >> 3;
    const int g   = o * 256 + threadIdx.x;
    const int pix = g * 4;
    const int xb  = pix & (WW - 1);
    const int y   = pix >> 9;

    float lsum = 0.f;

    for (int sl = 0; sl < 8; ++sl) {
        const int s = xcd * 8 + sl;
        const int b = s >> 3;
        const int t = s & 7;

        const float* f0 = flow     + (b * 16 + t) * HWSZ;
        const float* f1 = f0 + 8 * HWSZ;
        const float* g0 = flowback + (b * 16 + t) * HWSZ;
        const float* g1 = g0 + 8 * HWSZ;
        const float* mfp = mask_fw + s * HWSZ;
        const float* mbp = mask_bw + s * HWSZ;

        const float4 fxv = *(const float4*)(f0 + pix);
        const float4 fyv = *(const float4*)(f1 + pix);
        const float4 gxv = *(const float4*)(g0 + pix);
        const float4 gyv = *(const float4*)(g1 + pix);
        const float4 mfv = *(const float4*)(mfp + pix);
        const float4 mbv = *(const float4*)(mbp + pix);

        const float fxa[4] = {fxv.x, fxv.y, fxv.z, fxv.w};
        const float fya[4] = {fyv.x, fyv.y, fyv.z, fyv.w};
        const float gxa[4] = {gxv.x, gxv.y, gxv.z, gxv.w};
        const float gya[4] = {gyv.x, gyv.y, gyv.z, gyv.w};
        const float mfa[4] = {mfv.x, mfv.y, mfv.z, mfv.w};
        const float mba[4] = {mbv.x, mbv.y, mbv.z, mbv.w};

#pragma unroll
        for (int k = 0; k < 4; ++k) {
            const float xf = (float)(xb + k);
            const float yf = (float)y;
            float wfbx, wfby, wfx, wfy;
            bilin2(g0, g1, xf + fxa[k], yf + fya[k], wfbx, wfby);
            bilin2(f0, f1, xf + gxa[k], yf + gya[k], wfx, wfy);
            lsum += mfa[k] * (fabsf(wfbx + fxa[k]) + fabsf(wfby + fya[k]))
                  + mba[k] * (fabsf(wfx  + gxa[k]) + fabsf(wfy  + gya[k]));
        }
    }

    for (int off = 32; off > 0; off >>= 1)
        lsum += __shfl_down(lsum, off, 64);

    __shared__ float wsum[4];
    const int lane = threadIdx.x & 63;
    const int wv   = threadIdx.x >> 6;
    if (lane == 0) wsum[wv] = lsum;
    __syncthreads();
    if (threadIdx.x == 0) {
        float ssum = wsum[0] + wsum[1] + wsum[2] + wsum[3];
        atomicAdd(acc, (double)ssum);
    }
}

__global__ void finalize_kernel(const double* __restrict__ acc,
                                const int* __restrict__ npf,
                                float* __restrict__ out)
{
    out[0] = (float)(acc[0] * ((double)npf[0] / TOTAL_ELEMS));
}

extern "C" void kernel_launch(void* const* d_in, const int* in_sizes, int n_in,
                              void* d_out, int out_size, void* d_ws, size_t ws_size,
                              hipStream_t stream)
{
    const float* flow     = (const float*)d_in[0];
    const float* flowback = (const float*)d_in[1];
    const float* mask_fw  = (const float*)d_in[2];
    const float* mask_bw  = (const float*)d_in[3];
    const int*   npf      = (const int*)d_in[4];
    float*  out = (float*)d_out;
    double* acc = (double*)d_ws;

    (void)hipMemsetAsync(d_ws, 0, sizeof(double), stream);

    // Interleaved copies: 64 slices * 262144 px * 2 ch * 4B = 128 MiB each.
    const size_t ibytes = (size_t)NSL * HWSZ * 2 * sizeof(float);
    const size_t need   = 256 + 2 * ibytes;

    if (ws_size >= need) {
        float* flowI = (float*)((char*)d_ws + 256);
        float* fbI   = flowI + (size_t)NSL * HWSZ * 2;
        // 64 slices * 65536 groups / 256 threads = 16384 blocks
        repack_kernel<<<16384, 256, 0, stream>>>(flow, flowI);
        repack_kernel<<<16384, 256, 0, stream>>>(flowback, fbI);
        flow_loss_i_kernel<<<2048, 256, 0, stream>>>(flowI, fbI, mask_fw, mask_bw, acc);
    } else {
        flow_loss_kernel<<<2048, 256, 0, stream>>>(flow, flowback, mask_fw, mask_bw, acc);
    }
    finalize_kernel<<<1, 1, 0, stream>>>(acc, npf, out);
}

// Round 4
// 734.726 us; speedup vs baseline: 1.1525x; 1.1525x over previous
//
#include <hip/hip_runtime.h>

// Problem constants: flow/flowback [B,2,T,H,W] fp32, masks [B,1,T,H,W] fp32.
#define BB 8
#define CC 2
#define TT 8
#define HH 512
#define WW 512
#define HWSZ (HH * WW)                    // 262144 pixels per (b,t) slice
#define NSL (BB * TT)                     // 64 (b,t) slices
#define TOTAL_ELEMS ((double)(BB * CC * TT) * (double)HWSZ)  // 33,554,432 (mean denom)

// clang vector type accepted by nontemporal builtins (HIP_vector_type is not)
typedef float fvec4 __attribute__((ext_vector_type(4)));

// Unaligned-tolerant loads. gfx950 supports 4B-aligned dwordx2/dwordx4.
__device__ __forceinline__ float2 ld2u(const float* __restrict__ p) {
    float2 v;
    __builtin_memcpy(&v, p, sizeof(float2));
    return v;
}
__device__ __forceinline__ float4 ld4u(const float* __restrict__ p) {
    float4 v;
    __builtin_memcpy(&v, p, sizeof(float4));
    return v;
}
__device__ __forceinline__ fvec4 ld4nt(const float* __restrict__ p) {
    return __builtin_nontemporal_load((const fvec4*)p);
}

// ---------------------------------------------------------------------------
// Repack pass: [B,2,T,H,W] plane-separated -> [slice][H][W][2] interleaved.
// Nontemporal both sides: do not dirty L2 (the 216 MiB writeback storm was
// landing inside the gather dispatch), do not pollute it with streamed reads.
// ---------------------------------------------------------------------------
__global__ __launch_bounds__(256) void repack_nt_kernel(
    const float* __restrict__ in,   // [B,2,T,H,W]
    float* __restrict__ out)        // [64][H][W][2]
{
    const int g = blockIdx.x * 256 + threadIdx.x;  // float4-group id
    const int s = g >> 16;                         // 65536 groups per slice
    const int p = (g & 65535) * 4;                 // pixel index in slice
    const int b = s >> 3;                          // T == 8
    const int t = s & 7;
    const float* c0 = in + (b * 16 + t) * HWSZ;    // ((b*2+0)*8+t)*HWSZ
    const float* c1 = c0 + 8 * HWSZ;               // channel stride T*HWSZ
    const fvec4 a = ld4nt(c0 + p);
    const fvec4 c = ld4nt(c1 + p);
    float* o = out + (size_t)s * (HWSZ * 2) + (size_t)p * 2;
    fvec4 lo = {a.x, c.x, a.y, c.y};               // px p, p+1
    fvec4 hi = {a.z, c.z, a.w, c.w};               // px p+2, p+3
    __builtin_nontemporal_store(lo, (fvec4*)o);
    __builtin_nontemporal_store(hi, (fvec4*)(o + 4));
}

// ---------------------------------------------------------------------------
// Bilinear sample descriptor for channel-interleaved image [(y*W+x)*2 + c],
// zeros padding, align_corners=True. Address+weight math only — the loads are
// issued by the caller in batches so many divergent loads are in flight.
// ---------------------------------------------------------------------------
struct Samp { int bA, bB; float wl, wr, wA, wB; };

__device__ __forceinline__ Samp mkSamp(float sx, float sy)
{
    Samp s;
    const float x0f = floorf(sx);
    const float y0f = floorf(sy);
    const float wx1 = sx - x0f;
    const float wy1 = sy - y0f;
    const int x0 = (int)x0f;
    const int y0 = (int)y0f;
    const int y1 = y0 + 1;

    // x-pair window: pixels [xl, xl+1] with xl = clamp(x0, 0, W-2).
    const int xl = min(max(x0, 0), WW - 2);
    const float ax = (1.f - wx1) * ((x0 >= 0 && x0 < WW) ? 1.f : 0.f);      // tap x0
    const float bx = wx1 * ((x0 + 1 >= 0 && x0 + 1 < WW) ? 1.f : 0.f);      // tap x0+1
    const bool lo_is_x0 = (x0 == xl);
    s.wl = lo_is_x0 ? ax : bx;   // weight on loaded pixel xl
    s.wr = lo_is_x0 ? bx : ax;   // weight on loaded pixel xl+1

    s.wA = (1.f - wy1) * ((y0 >= 0 && y0 < HH) ? 1.f : 0.f);
    s.wB = wy1 * ((y1 >= 0 && y1 < HH) ? 1.f : 0.f);
    s.bA = (min(max(y0, 0), HH - 1) * WW + xl) * 2;
    s.bB = (min(max(y1, 0), HH - 1) * WW + xl) * 2;
    return s;
}

__device__ __forceinline__ float evalSamp(const Samp& s, const float4& A, const float4& B,
                                          int ch)  // ch 0: (.x,.z)  ch 1: (.y,.w)
{
    if (ch == 0)
        return s.wA * (s.wl * A.x + s.wr * A.z) + s.wB * (s.wl * B.x + s.wr * B.z);
    else
        return s.wA * (s.wl * A.y + s.wr * A.w) + s.wB * (s.wl * B.y + s.wr * B.w);
}

// Grid: 2048 blocks x 256 threads. blockIdx&7 = XCD (dispatch heuristic);
// each XCD owns 8 consecutive slices; per-slice gather window (flow+flowback
// interleaved = 4MB) matches the per-XCD L2. launch_bounds min-waves relaxed
// 6->4 so the allocator can keep 8 divergent dwordx4 results in flight.
__global__ __launch_bounds__(256, 4) void flow_loss_i_kernel(
    const float* __restrict__ flowI,
    const float* __restrict__ fbI,
    const float* __restrict__ mask_fw,
    const float* __restrict__ mask_bw,
    double* __restrict__ acc)
{
    const int xcd = blockIdx.x & 7;     // 0..7
    const int o   = blockIdx.x >> 3;    // 0..255: within-XCD block ordinal

    const int g   = o * 256 + threadIdx.x;  // 0..65535 float4-group in slice
    const int pix = g * 4;                  // 4 | 512 -> never straddles a row
    const int xb  = pix & (WW - 1);
    const int y   = pix >> 9;               // W == 512

    float lsum = 0.f;

    for (int sl = 0; sl < 8; ++sl) {
        const int s = xcd * 8 + sl;     // bt slice 0..63
        const float* fI  = flowI + (size_t)s * (HWSZ * 2);
        const float* gI  = fbI   + (size_t)s * (HWSZ * 2);
        const float* mfp = mask_fw + s * HWSZ;
        const float* mbp = mask_bw + s * HWSZ;

        // streamed reads (all coalesced 16B)
        const float4 u0 = *(const float4*)(fI + (size_t)pix * 2);
        const float4 u1 = *(const float4*)(fI + (size_t)pix * 2 + 4);
        const float4 v0 = *(const float4*)(gI + (size_t)pix * 2);
        const float4 v1 = *(const float4*)(gI + (size_t)pix * 2 + 4);
        const fvec4 mfv = ld4nt(mfp + pix);
        const fvec4 mbv = ld4nt(mbp + pix);

        const float fxa[4] = {u0.x, u0.z, u1.x, u1.z};
        const float fya[4] = {u0.y, u0.w, u1.y, u1.w};
        const float gxa[4] = {v0.x, v0.z, v1.x, v1.z};
        const float gya[4] = {v0.y, v0.w, v1.y, v1.w};
        const float mfa[4] = {mfv.x, mfv.y, mfv.z, mfv.w};
        const float mba[4] = {mbv.x, mbv.y, mbv.z, mbv.w};

        const float yf = (float)y;

        // 2-pixel batches: 4 samples -> 8 divergent dwordx4 issued back-to-back
        // before any consumption (MLP: ~8 outstanding per wave).
#pragma unroll
        for (int kk = 0; kk < 4; kk += 2) {
            const float xf0 = (float)(xb + kk);
            const float xf1 = (float)(xb + kk + 1);

            // nextloss: warp(flowback, flow) -> sample gI at flow coords
            const Samp s0 = mkSamp(xf0 + fxa[kk],     yf + fya[kk]);
            const Samp s1 = mkSamp(xf1 + fxa[kk + 1], yf + fya[kk + 1]);
            // prevloss: warp(flow, flowback) -> sample fI at flowback coords
            const Samp s2 = mkSamp(xf0 + gxa[kk],     yf + gya[kk]);
            const Samp s3 = mkSamp(xf1 + gxa[kk + 1], yf + gya[kk + 1]);

            const float4 A0 = ld4u(gI + s0.bA);
            const float4 B0 = ld4u(gI + s0.bB);
            const float4 A1 = ld4u(gI + s1.bA);
            const float4 B1 = ld4u(gI + s1.bB);
            const float4 A2 = ld4u(fI + s2.bA);
            const float4 B2 = ld4u(fI + s2.bB);
            const float4 A3 = ld4u(fI + s3.bA);
            const float4 B3 = ld4u(fI + s3.bB);

            const float w0x = evalSamp(s0, A0, B0, 0);
            const float w0y = evalSamp(s0, A0, B0, 1);
            const float w1x = evalSamp(s1, A1, B1, 0);
            const float w1y = evalSamp(s1, A1, B1, 1);
            const float w2x = evalSamp(s2, A2, B2, 0);
            const float w2y = evalSamp(s2, A2, B2, 1);
            const float w3x = evalSamp(s3, A3, B3, 0);
            const float w3y = evalSamp(s3, A3, B3, 1);

            lsum += mfa[kk]     * (fabsf(w0x + fxa[kk])     + fabsf(w0y + fya[kk]))
                  + mfa[kk + 1] * (fabsf(w1x + fxa[kk + 1]) + fabsf(w1y + fya[kk + 1]))
                  + mba[kk]     * (fabsf(w2x + gxa[kk])     + fabsf(w2y + gya[kk]))
                  + mba[kk + 1] * (fabsf(w3x + gxa[kk + 1]) + fabsf(w3y + gya[kk + 1]));
        }
    }

    // wave64 reduce
    for (int off = 32; off > 0; off >>= 1)
        lsum += __shfl_down(lsum, off, 64);

    __shared__ float wsum[4];
    const int lane = threadIdx.x & 63;
    const int wv   = threadIdx.x >> 6;
    if (lane == 0) wsum[wv] = lsum;
    __syncthreads();
    if (threadIdx.x == 0) {
        float ssum = wsum[0] + wsum[1] + wsum[2] + wsum[3];
        atomicAdd(acc, (double)ssum);
    }
}

// ---------------------------------------------------------------------------
// Fallback path (verified): used when ws_size can't hold the interleaved
// copies. Plane-separated layout, 4x 8B divergent loads per tap.
// ---------------------------------------------------------------------------
__device__ __forceinline__ void bilin2(const float* __restrict__ c0,
                                       const float* __restrict__ c1,
                                       float sx, float sy,
                                       float& r0, float& r1)
{
    const float x0f = floorf(sx);
    const float y0f = floorf(sy);
    const float wx1 = sx - x0f;
    const float wy1 = sy - y0f;
    const int x0 = (int)x0f;
    const int y0 = (int)y0f;
    const int y1 = y0 + 1;

    const int xl = min(max(x0, 0), WW - 2);
    const float ax = (1.f - wx1) * ((x0 >= 0 && x0 < WW) ? 1.f : 0.f);
    const float bx = wx1 * ((x0 + 1 >= 0 && x0 + 1 < WW) ? 1.f : 0.f);
    const bool lo_is_x0 = (x0 == xl);
    const float wl = lo_is_x0 ? ax : bx;
    const float wr = lo_is_x0 ? bx : ax;

    const float wyA = (1.f - wy1) * ((y0 >= 0 && y0 < HH) ? 1.f : 0.f);
    const float wyB = wy1 * ((y1 >= 0 && y1 < HH) ? 1.f : 0.f);
    const int baseA = min(max(y0, 0), HH - 1) * WW + xl;
    const int baseB = min(max(y1, 0), HH - 1) * WW + xl;

    const float2 a0 = ld2u(c0 + baseA);
    const float2 b0 = ld2u(c0 + baseB);
    const float2 a1 = ld2u(c1 + baseA);
    const float2 b1 = ld2u(c1 + baseB);

    r0 = wyA * (wl * a0.x + wr * a0.y) + wyB * (wl * b0.x + wr * b0.y);
    r1 = wyA * (wl * a1.x + wr * a1.y) + wyB * (wl * b1.x + wr * b1.y);
}

__global__ __launch_bounds__(256, 6) void flow_loss_kernel(
    const float* __restrict__ flow,
    const float* __restrict__ flowback,
    const float* __restrict__ mask_fw,
    const float* __restrict__ mask_bw,
    double* __restrict__ acc)
{
    const int xcd = blockIdx.x & 7;
    const int o   = blockIdx.x >> 3;
    const int g   = o * 256 + threadIdx.x;
    const int pix = g * 4;
    const int xb  = pix & (WW - 1);
    const int y   = pix >> 9;

    float lsum = 0.f;

    for (int sl = 0; sl < 8; ++sl) {
        const int s = xcd * 8 + sl;
        const int b = s >> 3;
        const int t = s & 7;

        const float* f0 = flow     + (b * 16 + t) * HWSZ;
        const float* f1 = f0 + 8 * HWSZ;
        const float* g0 = flowback + (b * 16 + t) * HWSZ;
        const float* g1 = g0 + 8 * HWSZ;
        const float* mfp = mask_fw + s * HWSZ;
        const float* mbp = mask_bw + s * HWSZ;

        const float4 fxv = *(const float4*)(f0 + pix);
        const float4 fyv = *(const float4*)(f1 + pix);
        const float4 gxv = *(const float4*)(g0 + pix);
        const float4 gyv = *(const float4*)(g1 + pix);
        const float4 mfv = *(const float4*)(mfp + pix);
        const float4 mbv = *(const float4*)(mbp + pix);

        const float fxa[4] = {fxv.x, fxv.y, fxv.z, fxv.w};
        const float fya[4] = {fyv.x, fyv.y, fyv.z, fyv.w};
        const float gxa[4] = {gxv.x, gxv.y, gxv.z, gxv.w};
        const float gya[4] = {gyv.x, gyv.y, gyv.z, gyv.w};
        const float mfa[4] = {mfv.x, mfv.y, mfv.z, mfv.w};
        const float mba[4] = {mbv.x, mbv.y, mbv.z, mbv.w};

#pragma unroll
        for (int k = 0; k < 4; ++k) {
            const float xf = (float)(xb + k);
            const float yf = (float)y;
            float wfbx, wfby, wfx, wfy;
            bilin2(g0, g1, xf + fxa[k], yf + fya[k], wfbx, wfby);
            bilin2(f0, f1, xf + gxa[k], yf + gya[k], wfx, wfy);
            lsum += mfa[k] * (fabsf(wfbx + fxa[k]) + fabsf(wfby + fya[k]))
                  + mba[k] * (fabsf(wfx  + gxa[k]) + fabsf(wfy  + gya[k]));
        }
    }

    for (int off = 32; off > 0; off >>= 1)
        lsum += __shfl_down(lsum, off, 64);

    __shared__ float wsum[4];
    const int lane = threadIdx.x & 63;
    const int wv   = threadIdx.x >> 6;
    if (lane == 0) wsum[wv] = lsum;
    __syncthreads();
    if (threadIdx.x == 0) {
        float ssum = wsum[0] + wsum[1] + wsum[2] + wsum[3];
        atomicAdd(acc, (double)ssum);
    }
}

__global__ void finalize_kernel(const double* __restrict__ acc,
                                const int* __restrict__ npf,
                                float* __restrict__ out)
{
    out[0] = (float)(acc[0] * ((double)npf[0] / TOTAL_ELEMS));
}

extern "C" void kernel_launch(void* const* d_in, const int* in_sizes, int n_in,
                              void* d_out, int out_size, void* d_ws, size_t ws_size,
                              hipStream_t stream)
{
    const float* flow     = (const float*)d_in[0];
    const float* flowback = (const float*)d_in[1];
    const float* mask_fw  = (const float*)d_in[2];
    const float* mask_bw  = (const float*)d_in[3];
    const int*   npf      = (const int*)d_in[4];
    float*  out = (float*)d_out;
    double* acc = (double*)d_ws;

    (void)hipMemsetAsync(d_ws, 0, sizeof(double), stream);

    // Interleaved copies: 64 slices * 262144 px * 2 ch * 4B = 128 MiB each.
    const size_t ibytes = (size_t)NSL * HWSZ * 2 * sizeof(float);
    const size_t need   = 256 + 2 * ibytes;

    if (ws_size >= need) {
        float* flowI = (float*)((char*)d_ws + 256);
        float* fbI   = flowI + (size_t)NSL * HWSZ * 2;
        // 64 slices * 65536 groups / 256 threads = 16384 blocks
        repack_nt_kernel<<<16384, 256, 0, stream>>>(flow, flowI);
        repack_nt_kernel<<<16384, 256, 0, stream>>>(flowback, fbI);
        flow_loss_i_kernel<<<2048, 256, 0, stream>>>(flowI, fbI, mask_fw, mask_bw, acc);
    } else {
        flow_loss_kernel<<<2048, 256, 0, stream>>>(flow, flowback, mask_fw, mask_bw, acc);
    }
    finalize_kernel<<<1, 1, 0, stream>>>(acc, npf, out);
}